// Round 6
// baseline (347.890 us; speedup 1.0000x reference)
//
#include <hip/hip_runtime.h>
#include <hip/hip_cooperative_groups.h>
#include <math.h>

#define B_   32
#define S_   512
#define D_   768
#define C_   128   // MAX_CHUNK_NUMBER
#define LCK  8     // MAX_CHUNK_LEN

#define MT      32               // rows per logits tile
#define NTILE   12               // tiles per batch (Tb <= 3*128 = 384)
#define P1_UNITS (NTILE * B_)    // 384

typedef _Float16 half8_t __attribute__((ext_vector_type(8)));
typedef float    f32x4   __attribute__((ext_vector_type(4)));

struct Args {
    const float* X; const int* lens; const float* W;
    const float* db; const float* ab; const float* q;
    const float* lnw; const float* lnb;
    float* cf; float* sent;
    int* starts; int* Tb; float* Lc;
    _Float16* Wh; float* partial;
};

__device__ __forceinline__ float fast_tanh(float x) {
    float e = __expf(2.0f * x);
    return 1.0f - 2.0f / (e + 1.0f);   // exact saturation at +/-inf
}

// ---------------- P0: W fp32->fp16 | per-batch scan | Lc ----------------
__device__ void phase0(const Args a, int bid, int nb) {
    const int tid = threadIdx.x;
    // W convert, grid-strided (73728 half8 units)
    const int units = D_ * D_ / 8;
    for (int u = bid * 256 + tid; u < units; u += nb * 256) {
        const float* src = a.W + (size_t)u * 8;
        float4 f0 = *(const float4*)src;
        float4 f1 = *(const float4*)(src + 4);
        half8_t h;
        h[0] = (_Float16)f0.x; h[1] = (_Float16)f0.y;
        h[2] = (_Float16)f0.z; h[3] = (_Float16)f0.w;
        h[4] = (_Float16)f1.x; h[5] = (_Float16)f1.y;
        h[6] = (_Float16)f1.z; h[7] = (_Float16)f1.w;
        *(half8_t*)(a.Wh + (size_t)u * 8) = h;
    }
    if (bid < B_) {
        // uniform-barrier exclusive scan of chunk_lens (all 256 threads participate)
        int b = bid;
        __shared__ int s_scan[256];
        int v = (tid < C_) ? a.lens[b * C_ + tid] : 0;
        s_scan[tid] = v;
        __syncthreads();
        #pragma unroll
        for (int off = 1; off < C_; off <<= 1) {
            int add = (tid >= off) ? s_scan[tid - off] : 0;
            __syncthreads();
            s_scan[tid] += add;
            __syncthreads();
        }
        if (tid < C_) {
            a.starts[b * C_ + tid] = s_scan[tid] - v;
            if (tid == C_ - 1) a.Tb[b] = s_scan[C_ - 1];
        }
    } else if (bid == B_) {
        // Lc = sum_e q[e]*tanh(db[e]+ab[e])
        __shared__ float s_lcred[256];
        float p = 0.f;
        for (int e = tid; e < D_; e += 256) p += fast_tanh(a.db[e] + a.ab[e]) * a.q[e];
        s_lcred[tid] = p;
        __syncthreads();
        for (int off = 128; off > 0; off >>= 1) {
            if (tid < off) s_lcred[tid] += s_lcred[tid + off];
            __syncthreads();
        }
        if (tid == 0) *a.Lc = s_lcred[0];
    }
}

// ---------------- P1: logits GEMM (X-resident regs, W direct L2->reg) ----------------
// logit[b,t] = sum_e q[e]*tanh( sum_d X[b,t,d]*W[e,d] + db[e]+ab[e] )
// A-frag (16x16x32 f16): lane holds A[m0+mt*16+(l&15)][ks*32+(l>>4)*8+j], j=0..7
// B-frag: lane holds W[e][same k], e = wid*192 + nt*16 + (l&15)
// C/D: col=lane&15 (e), row=(lane>>4)*4+r (m)  [validated rounds 3-4]
__device__ void phase1(const Args a, int bid, int nb) {
    const int tid = threadIdx.x, lane = tid & 63, wid = tid >> 6;
    __shared__ float s_red[4][32];
    for (int u = bid; u < P1_UNITS; u += nb) {
        int b  = u / NTILE;
        int mi = u % NTILE;
        int m0 = mi * MT;
        if (m0 >= a.Tb[b]) continue;   // block-uniform

        half8_t A[2][24];
        {
            const float* Xb = a.X + (size_t)b * S_ * D_;
            #pragma unroll
            for (int mt = 0; mt < 2; ++mt) {
                const float* Xr = Xb + (size_t)(m0 + mt * 16 + (lane & 15)) * D_ + ((lane >> 4) * 8);
                #pragma unroll
                for (int ks = 0; ks < 24; ++ks) {
                    float4 f0 = *(const float4*)(Xr + ks * 32);
                    float4 f1 = *(const float4*)(Xr + ks * 32 + 4);
                    half8_t h;
                    h[0] = (_Float16)f0.x; h[1] = (_Float16)f0.y;
                    h[2] = (_Float16)f0.z; h[3] = (_Float16)f0.w;
                    h[4] = (_Float16)f1.x; h[5] = (_Float16)f1.y;
                    h[6] = (_Float16)f1.z; h[7] = (_Float16)f1.w;
                    A[mt][ks] = h;
                }
            }
        }

        float lsum[2][4] = {{0.f,0.f,0.f,0.f},{0.f,0.f,0.f,0.f}};
        const int ebase = wid * 192 + (lane & 15);
        const int krow  = (lane >> 4) * 8;
        #pragma unroll 1
        for (int nt = 0; nt < 12; ++nt) {
            const int e = ebase + nt * 16;
            const _Float16* bb = a.Wh + (size_t)e * D_ + krow;
            f32x4 acc0 = (f32x4)(0.f), acc1 = (f32x4)(0.f);
            #pragma unroll
            for (int ks = 0; ks < 24; ++ks) {
                half8_t bv = *(const half8_t*)(bb + ks * 32);
                acc0 = __builtin_amdgcn_mfma_f32_16x16x32_f16(A[0][ks], bv, acc0, 0, 0, 0);
                acc1 = __builtin_amdgcn_mfma_f32_16x16x32_f16(A[1][ks], bv, acc1, 0, 0, 0);
            }
            float beta = a.db[e] + a.ab[e];
            float qe = a.q[e];
            #pragma unroll
            for (int r = 0; r < 4; ++r) {
                lsum[0][r] += fast_tanh(acc0[r] + beta) * qe;
                lsum[1][r] += fast_tanh(acc1[r] + beta) * qe;
            }
        }
        // sum the 16 e-lanes
        #pragma unroll
        for (int off = 1; off < 16; off <<= 1)
            #pragma unroll
            for (int mt = 0; mt < 2; ++mt)
                #pragma unroll
                for (int r = 0; r < 4; ++r)
                    lsum[mt][r] += __shfl_xor(lsum[mt][r], off, 64);
        // combine 4 waves (192-col slices each) via LDS
        __syncthreads();
        if ((lane & 15) == 0) {
            #pragma unroll
            for (int mt = 0; mt < 2; ++mt)
                #pragma unroll
                for (int r = 0; r < 4; ++r)
                    s_red[wid][mt * 16 + (lane >> 4) * 4 + r] = lsum[mt][r];
        }
        __syncthreads();
        if (tid < MT)
            a.partial[(size_t)b * S_ + m0 + tid] =
                s_red[0][tid] + s_red[1][tid] + s_red[2][tid] + s_red[3][tid];
    }
}

// ---------------- P2: per-wave chunk softmax + weighted sum + LayerNorm ----------------
__device__ void phase2(const Args a, int bid, int nb) {
    const int tid = threadIdx.x, lane = tid & 63, wid = tid >> 6;
    const float LcV = *a.Lc;
    const int gw = bid * 4 + wid;
    const int nw = nb * 4;
    for (int cu = gw; cu < B_ * C_; cu += nw) {
        int b = cu >> 7, c = cu & 127;
        int len = a.lens[b * C_ + c];
        len = max(0, min(len, LCK));
        int start = a.starts[b * C_ + c];
        float lg[LCK];
        #pragma unroll
        for (int l = 0; l < LCK; ++l) {
            bool valid = l < len;
            int t = valid ? (start + l) : start;   // start <= Tb <= 384: in-bounds
            float v = a.partial[(size_t)b * S_ + t];
            lg[l] = valid ? v : LcV;
        }
        float m = lg[0];
        #pragma unroll
        for (int l = 1; l < LCK; ++l) m = fmaxf(m, lg[l]);
        float denom = 0.f;
        #pragma unroll
        for (int l = 0; l < LCK; ++l) { lg[l] = __expf(lg[l] - m); denom += lg[l]; }
        float inv = 1.0f / denom;

        const float* Xb = a.X + (size_t)b * S_ * D_;
        f32x4 o[3] = {(f32x4)(0.f), (f32x4)(0.f), (f32x4)(0.f)};
        for (int l = 0; l < len; ++l) {
            const float* row = Xb + (size_t)(start + l) * D_;
            float wgt = lg[l];
            #pragma unroll
            for (int p = 0; p < 3; ++p) {
                f32x4 xv = *(const f32x4*)(row + p * 256 + lane * 4);
                o[p] += xv * wgt;
            }
        }
        float sum = 0.f, sq = 0.f;
        #pragma unroll
        for (int p = 0; p < 3; ++p) {
            o[p] *= inv;
            #pragma unroll
            for (int j = 0; j < 4; ++j) { sum += o[p][j]; sq += o[p][j] * o[p][j]; }
        }
        #pragma unroll
        for (int off = 1; off < 64; off <<= 1) {
            sum += __shfl_xor(sum, off, 64);
            sq  += __shfl_xor(sq,  off, 64);
        }
        float u_   = sum * (1.0f / D_);
        float var  = fmaxf(sq * (1.0f / D_) - u_ * u_, 0.0f);
        float rstd = rsqrtf(var + 1e-12f);
        float* out = a.cf + ((size_t)b * C_ + c) * D_;
        #pragma unroll
        for (int p = 0; p < 3; ++p) {
            int d = p * 256 + lane * 4;
            f32x4 wv = *(const f32x4*)(a.lnw + d);
            f32x4 bv = *(const f32x4*)(a.lnb + d);
            f32x4 ov;
            #pragma unroll
            for (int j = 0; j < 4; ++j) ov[j] = wv[j] * ((o[p][j] - u_) * rstd) + bv[j];
            *(f32x4*)(out + d) = ov;
        }
    }
}

// ---------------- P3: sentence max over chunks ----------------
__device__ void phase3(const Args a, int bid, int nb) {
    const int tid = threadIdx.x;
    const int units = B_ * (D_ / 4);   // 6144 f32x4 columns
    for (int u = bid * 256 + tid; u < units; u += nb * 256) {
        int b  = u / (D_ / 4);
        int d4 = u % (D_ / 4);
        const float* p = a.cf + (size_t)b * C_ * D_ + (size_t)d4 * 4;
        f32x4 m = *(const f32x4*)p;
        #pragma unroll 4
        for (int c = 1; c < C_; ++c) {
            f32x4 v = *(const f32x4*)(p + (size_t)c * D_);
            #pragma unroll
            for (int j = 0; j < 4; ++j) m[j] = fmaxf(m[j], v[j]);
        }
        *(f32x4*)(a.sent + (size_t)b * D_ + (size_t)d4 * 4) = m;
    }
}

// ---------------- fused cooperative kernel ----------------
__global__ __launch_bounds__(256, 2) void fused_kernel(Args a) {
    cooperative_groups::grid_group grid = cooperative_groups::this_grid();
    phase0(a, blockIdx.x, gridDim.x);
    grid.sync();
    phase1(a, blockIdx.x, gridDim.x);
    grid.sync();
    phase2(a, blockIdx.x, gridDim.x);
    grid.sync();
    phase3(a, blockIdx.x, gridDim.x);
}

// ---------------- fallback: same phases, 4 plain launches ----------------
__global__ __launch_bounds__(256)    void k_prep  (Args a) { phase0(a, blockIdx.x, gridDim.x); }
__global__ __launch_bounds__(256, 2) void k_logits(Args a) { phase1(a, blockIdx.x, gridDim.x); }
__global__ __launch_bounds__(256)    void k_chunk (Args a) { phase2(a, blockIdx.x, gridDim.x); }
__global__ __launch_bounds__(256)    void k_max   (Args a) { phase3(a, blockIdx.x, gridDim.x); }

extern "C" void kernel_launch(void* const* d_in, const int* in_sizes, int n_in,
                              void* d_out, int out_size, void* d_ws, size_t ws_size,
                              hipStream_t stream) {
    Args a;
    a.X    = (const float*)d_in[0];   // (32,512,768)
    a.lens = (const int*)d_in[1];     // (32,128)
    a.W    = (const float*)d_in[2];   // (768,768)
    a.db   = (const float*)d_in[3];
    a.ab   = (const float*)d_in[4];
    a.q    = (const float*)d_in[5];
    a.lnw  = (const float*)d_in[6];
    a.lnb  = (const float*)d_in[7];

    a.cf   = (float*)d_out;                      // (32,128,768)
    a.sent = a.cf + (size_t)B_ * C_ * D_;        // (32,768)

    a.starts  = (int*)d_ws;                                  // 16 KB
    a.Tb      = (int*)((char*)d_ws + 16384);                 // 128 B
    a.Lc      = (float*)((char*)d_ws + 16640);               // 4 B
    a.Wh      = (_Float16*)((char*)d_ws + 32768);            // 1.125 MB
    a.partial = (float*)((char*)d_ws + 32768 + 1179648);     // 64 KB

    int dev = 0;
    (void)hipGetDevice(&dev);
    int coopOK = 0;
    (void)hipDeviceGetAttribute(&coopOK, hipDeviceAttributeCooperativeLaunch, dev);
    int occ = 0;
    hipError_t oe = hipOccupancyMaxActiveBlocksPerMultiprocessor(&occ, fused_kernel, 256, 0);
    if (oe != hipSuccess || occ < 1) occ = 1;

    bool launched = false;
    if (coopOK) {
        int blocks = occ * 256;                 // 256 CUs
        if (blocks > P1_UNITS) blocks = P1_UNITS;
        if (blocks < B_ + 1)  blocks = B_ + 1;  // P0 needs blocks 0..32
        void* kargs[] = { (void*)&a };
        hipError_t e = hipLaunchCooperativeKernel((const void*)fused_kernel,
                                                  dim3(blocks), dim3(256), kargs, 0, stream);
        if (e == hipSuccess) launched = true;
        else (void)hipGetLastError();           // clear and fall back
    }
    if (!launched) {
        k_prep  <<<256,      256, 0, stream>>>(a);
        k_logits<<<P1_UNITS, 256, 0, stream>>>(a);
        k_chunk <<<256,      256, 0, stream>>>(a);
        k_max   <<<96,       256, 0, stream>>>(a);
    }
}

// Round 7
// 264.251 us; speedup vs baseline: 1.3165x; 1.3165x over previous
//
#include <hip/hip_runtime.h>
#include <hip/hip_cooperative_groups.h>
#include <math.h>

#define B_   32
#define S_   512
#define D_   768
#define C_   128   // MAX_CHUNK_NUMBER
#define LCK  8     // MAX_CHUNK_LEN

#define MT      32                    // rows per logits tile
#define NTILE   12                    // tiles per batch (Tb <= 384)
#define EH      2                     // e-halves
#define P1_UNITS (B_ * NTILE * EH)    // 768

typedef _Float16 half8_t __attribute__((ext_vector_type(8)));
typedef float    f32x4   __attribute__((ext_vector_type(4)));

struct Args {
    const float* X; const int* lens; const float* W;
    const float* db; const float* ab; const float* q;
    const float* lnw; const float* lnb;
    float* cf; float* sent;
    int* starts; int* Tb; float* Lc;
    _Float16* Wh; float* partial;
};

__device__ __forceinline__ float fast_tanh(float x) {
    float e = __expf(2.0f * x);
    return 1.0f - 2.0f / (e + 1.0f);   // exact saturation at +/-inf
}

// ---------------- P0: W fp32->fp16 | per-batch scan | Lc ----------------
__device__ void phase0(const Args a, int bid, int nb) {
    const int tid = threadIdx.x;
    // W convert, grid-strided (73728 half8 units)
    const int units = D_ * D_ / 8;
    for (int u = bid * 256 + tid; u < units; u += nb * 256) {
        const float* src = a.W + (size_t)u * 8;
        float4 f0 = *(const float4*)src;
        float4 f1 = *(const float4*)(src + 4);
        half8_t h;
        h[0] = (_Float16)f0.x; h[1] = (_Float16)f0.y;
        h[2] = (_Float16)f0.z; h[3] = (_Float16)f0.w;
        h[4] = (_Float16)f1.x; h[5] = (_Float16)f1.y;
        h[6] = (_Float16)f1.z; h[7] = (_Float16)f1.w;
        *(half8_t*)(a.Wh + (size_t)u * 8) = h;
    }
    if (bid < B_) {
        // uniform-barrier exclusive scan of chunk_lens
        int b = bid;
        __shared__ int s_scan[256];
        int v = (tid < C_) ? a.lens[b * C_ + tid] : 0;
        s_scan[tid] = v;
        __syncthreads();
        #pragma unroll
        for (int off = 1; off < C_; off <<= 1) {
            int add = (tid >= off) ? s_scan[tid - off] : 0;
            __syncthreads();
            s_scan[tid] += add;
            __syncthreads();
        }
        if (tid < C_) {
            a.starts[b * C_ + tid] = s_scan[tid] - v;
            if (tid == C_ - 1) a.Tb[b] = s_scan[C_ - 1];
        }
    } else if (bid == B_) {
        __shared__ float s_lcred[256];
        float p = 0.f;
        for (int e = tid; e < D_; e += 256) p += fast_tanh(a.db[e] + a.ab[e]) * a.q[e];
        s_lcred[tid] = p;
        __syncthreads();
        for (int off = 128; off > 0; off >>= 1) {
            if (tid < off) s_lcred[tid] += s_lcred[tid + off];
            __syncthreads();
        }
        if (tid == 0) *a.Lc = s_lcred[0];
    }
}

// ---------------- P1: logits GEMM ----------------
// logit[b,t] = sum_e q[e]*tanh( sum_d X[b,t,d]*W[e,d] + db[e]+ab[e] )
// Per unit (b, 32-row tile, e-half): X tile staged ONCE to 48 KB LDS (fp16,
// XOR-swizzled); ks-outer loop: 2 ds_read A-frags + 6 global B-frags (L2-res
// fp16 W) + 12 MFMA into acc[2][6] (small persistent state, AGPR-able).
// A-frag (16x16x32 f16): lane holds A[m0+mt*16+(l&15)][ks*32+(l>>4)*8+j]
// B-frag: lane holds W[e][same k], e = eh*384+wid*96+nt*16+(l&15)
// C/D: col=lane&15 (e), row=(lane>>4)*4+r (m)   [validated rounds 3-6]
__device__ void phase1(const Args a, int bid, int nb, _Float16* Xs) {
    const int tid = threadIdx.x, lane = tid & 63, wid = tid >> 6;
    __shared__ float s_red[4][32];
    const int erow = lane & 15;
    const int krow = (lane >> 4) * 8;

    for (int u = bid; u < P1_UNITS; u += nb) {
        int b    = u / (NTILE * EH);
        int rem  = u % (NTILE * EH);
        int tile = rem >> 1;
        int eh   = rem & 1;
        int m0   = tile * MT;
        if (m0 >= a.Tb[b]) continue;   // block-uniform

        // ---- stage X tile (32 rows x 768 k) fp32 -> fp16 LDS, swizzled ----
        {
            const float* Xb = a.X + ((size_t)(b * S_ + m0)) * D_;
            #pragma unroll
            for (int it = 0; it < 12; ++it) {
                int idx = it * 256 + tid;        // 0..3071 half8 units
                int row = idx / 96;
                int kk8 = idx % 96;
                const float* src = Xb + (size_t)row * D_ + kk8 * 8;
                float4 f0 = *(const float4*)src;
                float4 f1 = *(const float4*)(src + 4);
                half8_t h;
                h[0] = (_Float16)f0.x; h[1] = (_Float16)f0.y;
                h[2] = (_Float16)f0.z; h[3] = (_Float16)f0.w;
                h[4] = (_Float16)f1.x; h[5] = (_Float16)f1.y;
                h[6] = (_Float16)f1.z; h[7] = (_Float16)f1.w;
                int byte = row * 1536 + kk8 * 16;
                byte ^= (row & 7) << 4;
                *(half8_t*)((char*)Xs + byte) = h;
            }
        }
        __syncthreads();

        // ---- ks-outer MFMA loop ----
        const int ebase = eh * 384 + wid * 96 + erow;
        const _Float16* Bb = a.Wh + (size_t)ebase * D_ + krow;
        f32x4 acc[2][6];
        #pragma unroll
        for (int mt = 0; mt < 2; ++mt)
            #pragma unroll
            for (int nt = 0; nt < 6; ++nt) acc[mt][nt] = (f32x4)(0.f);

        #pragma unroll 2
        for (int ks = 0; ks < 24; ++ks) {
            half8_t av[2];
            #pragma unroll
            for (int mt = 0; mt < 2; ++mt) {
                int row  = mt * 16 + erow;
                int byte = row * 1536 + (ks * 32 + krow) * 2;
                byte ^= (row & 7) << 4;
                av[mt] = *(const half8_t*)((const char*)Xs + byte);
            }
            #pragma unroll
            for (int nt = 0; nt < 6; ++nt) {
                half8_t bv = *(const half8_t*)(Bb + (size_t)nt * 16 * D_ + ks * 32);
                acc[0][nt] = __builtin_amdgcn_mfma_f32_16x16x32_f16(av[0], bv, acc[0][nt], 0, 0, 0);
                acc[1][nt] = __builtin_amdgcn_mfma_f32_16x16x32_f16(av[1], bv, acc[1][nt], 0, 0, 0);
            }
        }

        // ---- epilogue: tanh + q-dot ----
        float lsum[2][4] = {{0.f,0.f,0.f,0.f},{0.f,0.f,0.f,0.f}};
        #pragma unroll
        for (int nt = 0; nt < 6; ++nt) {
            int e = ebase + nt * 16;
            float beta = a.db[e] + a.ab[e];
            float qe = a.q[e];
            #pragma unroll
            for (int r = 0; r < 4; ++r) {
                lsum[0][r] += fast_tanh(acc[0][nt][r] + beta) * qe;
                lsum[1][r] += fast_tanh(acc[1][nt][r] + beta) * qe;
            }
        }
        #pragma unroll
        for (int off = 1; off < 16; off <<= 1)
            #pragma unroll
            for (int mt = 0; mt < 2; ++mt)
                #pragma unroll
                for (int r = 0; r < 4; ++r)
                    lsum[mt][r] += __shfl_xor(lsum[mt][r], off, 64);

        __syncthreads();   // Xs reads done; also guards s_red reuse
        if (erow == 0) {
            #pragma unroll
            for (int mt = 0; mt < 2; ++mt)
                #pragma unroll
                for (int r = 0; r < 4; ++r)
                    s_red[wid][mt * 16 + (lane >> 4) * 4 + r] = lsum[mt][r];
        }
        __syncthreads();
        if (tid < MT)
            a.partial[((size_t)eh * B_ + b) * S_ + m0 + tid] =
                s_red[0][tid] + s_red[1][tid] + s_red[2][tid] + s_red[3][tid];
    }
}

// ---------------- P2: per-wave chunk softmax + weighted sum + LayerNorm ----------------
__device__ void phase2(const Args a, int bid, int nb) {
    const int tid = threadIdx.x, lane = tid & 63, wid = tid >> 6;
    const float LcV = *a.Lc;
    const int gw = bid * 4 + wid;
    const int nw = nb * 4;
    for (int cu = gw; cu < B_ * C_; cu += nw) {
        int b = cu >> 7, c = cu & 127;
        int len = a.lens[b * C_ + c];
        len = max(0, min(len, LCK));
        int start = a.starts[b * C_ + c];
        float lg[LCK];
        #pragma unroll
        for (int l = 0; l < LCK; ++l) {
            bool valid = l < len;
            int t = valid ? (start + l) : start;   // start <= 384 < 512: in-bounds
            float v = a.partial[(size_t)b * S_ + t] + a.partial[((size_t)B_ + b) * S_ + t];
            lg[l] = valid ? v : LcV;
        }
        float m = lg[0];
        #pragma unroll
        for (int l = 1; l < LCK; ++l) m = fmaxf(m, lg[l]);
        float denom = 0.f;
        #pragma unroll
        for (int l = 0; l < LCK; ++l) { lg[l] = __expf(lg[l] - m); denom += lg[l]; }
        float inv = 1.0f / denom;

        const float* Xb = a.X + (size_t)b * S_ * D_;
        f32x4 o[3] = {(f32x4)(0.f), (f32x4)(0.f), (f32x4)(0.f)};
        for (int l = 0; l < len; ++l) {
            const float* row = Xb + (size_t)(start + l) * D_;
            float wgt = lg[l];
            #pragma unroll
            for (int p = 0; p < 3; ++p) {
                f32x4 xv = *(const f32x4*)(row + p * 256 + lane * 4);
                o[p] += xv * wgt;
            }
        }
        float sum = 0.f, sq = 0.f;
        #pragma unroll
        for (int p = 0; p < 3; ++p) {
            o[p] *= inv;
            #pragma unroll
            for (int j = 0; j < 4; ++j) { sum += o[p][j]; sq += o[p][j] * o[p][j]; }
        }
        #pragma unroll
        for (int off = 1; off < 64; off <<= 1) {
            sum += __shfl_xor(sum, off, 64);
            sq  += __shfl_xor(sq,  off, 64);
        }
        float u_   = sum * (1.0f / D_);
        float var  = fmaxf(sq * (1.0f / D_) - u_ * u_, 0.0f);
        float rstd = rsqrtf(var + 1e-12f);
        float* out = a.cf + ((size_t)b * C_ + c) * D_;
        #pragma unroll
        for (int p = 0; p < 3; ++p) {
            int d = p * 256 + lane * 4;
            f32x4 wv = *(const f32x4*)(a.lnw + d);
            f32x4 bv = *(const f32x4*)(a.lnb + d);
            f32x4 ov;
            #pragma unroll
            for (int j = 0; j < 4; ++j) ov[j] = wv[j] * ((o[p][j] - u_) * rstd) + bv[j];
            *(f32x4*)(out + d) = ov;
        }
    }
}

// ---------------- P3: sentence max over chunks ----------------
__device__ void phase3(const Args a, int bid, int nb) {
    const int tid = threadIdx.x;
    const int units = B_ * (D_ / 4);
    for (int u = bid * 256 + tid; u < units; u += nb * 256) {
        int b  = u / (D_ / 4);
        int d4 = u % (D_ / 4);
        const float* p = a.cf + (size_t)b * C_ * D_ + (size_t)d4 * 4;
        f32x4 m = *(const f32x4*)p;
        #pragma unroll 4
        for (int c = 1; c < C_; ++c) {
            f32x4 v = *(const f32x4*)(p + (size_t)c * D_);
            #pragma unroll
            for (int j = 0; j < 4; ++j) m[j] = fmaxf(m[j], v[j]);
        }
        *(f32x4*)(a.sent + (size_t)b * D_ + (size_t)d4 * 4) = m;
    }
}

// ---------------- fused cooperative kernel ----------------
__global__ __launch_bounds__(256, 2) void fused_kernel(Args a) {
    __shared__ _Float16 Xs[MT * D_];   // 48 KB
    cooperative_groups::grid_group grid = cooperative_groups::this_grid();
    phase0(a, blockIdx.x, gridDim.x);
    grid.sync();
    phase1(a, blockIdx.x, gridDim.x, Xs);
    grid.sync();
    phase2(a, blockIdx.x, gridDim.x);
    grid.sync();
    phase3(a, blockIdx.x, gridDim.x);
}

// ---------------- fallback: same phases, 4 plain launches ----------------
__global__ __launch_bounds__(256)    void k_prep  (Args a) { phase0(a, blockIdx.x, gridDim.x); }
__global__ __launch_bounds__(256, 2) void k_logits(Args a) {
    __shared__ _Float16 Xs[MT * D_];
    phase1(a, blockIdx.x, gridDim.x, Xs);
}
__global__ __launch_bounds__(256)    void k_chunk (Args a) { phase2(a, blockIdx.x, gridDim.x); }
__global__ __launch_bounds__(256)    void k_max   (Args a) { phase3(a, blockIdx.x, gridDim.x); }

extern "C" void kernel_launch(void* const* d_in, const int* in_sizes, int n_in,
                              void* d_out, int out_size, void* d_ws, size_t ws_size,
                              hipStream_t stream) {
    Args a;
    a.X    = (const float*)d_in[0];   // (32,512,768)
    a.lens = (const int*)d_in[1];     // (32,128)
    a.W    = (const float*)d_in[2];   // (768,768)
    a.db   = (const float*)d_in[3];
    a.ab   = (const float*)d_in[4];
    a.q    = (const float*)d_in[5];
    a.lnw  = (const float*)d_in[6];
    a.lnb  = (const float*)d_in[7];

    a.cf   = (float*)d_out;                      // (32,128,768)
    a.sent = a.cf + (size_t)B_ * C_ * D_;        // (32,768)

    a.starts  = (int*)d_ws;                                  // 16 KB
    a.Tb      = (int*)((char*)d_ws + 16384);                 // 128 B
    a.Lc      = (float*)((char*)d_ws + 16640);               // 4 B
    a.Wh      = (_Float16*)((char*)d_ws + 32768);            // 1.125 MB
    a.partial = (float*)((char*)d_ws + 32768 + 1179648);     // 2*32*512*4 = 128 KB

    int dev = 0;
    (void)hipGetDevice(&dev);
    int coopOK = 0;
    (void)hipDeviceGetAttribute(&coopOK, hipDeviceAttributeCooperativeLaunch, dev);
    int occ = 0;
    hipError_t oe = hipOccupancyMaxActiveBlocksPerMultiprocessor(&occ, fused_kernel, 256, 0);
    if (oe != hipSuccess || occ < 1) occ = 1;

    bool launched = false;
    if (coopOK) {
        int blocks = occ * 256;                 // 256 CUs
        if (blocks > P1_UNITS) blocks = P1_UNITS;
        if (blocks < B_ + 1)  blocks = B_ + 1;  // P0 needs blocks 0..32
        void* kargs[] = { (void*)&a };
        hipError_t e = hipLaunchCooperativeKernel((const void*)fused_kernel,
                                                  dim3(blocks), dim3(256), kargs, 0, stream);
        if (e == hipSuccess) launched = true;
        else (void)hipGetLastError();           // clear and fall back
    }
    if (!launched) {
        k_prep  <<<256,      256, 0, stream>>>(a);
        k_logits<<<P1_UNITS, 256, 0, stream>>>(a);
        k_chunk <<<512,      256, 0, stream>>>(a);
        k_max   <<<96,       256, 0, stream>>>(a);
    }
}

// Round 9
// 154.424 us; speedup vs baseline: 2.2528x; 1.7112x over previous
//
#include <hip/hip_runtime.h>
#include <math.h>

#define B_   32
#define S_   512
#define D_   768
#define C_   128   // MAX_CHUNK_NUMBER
#define LCK  8     // MAX_CHUNK_LEN

#define MT     32                 // rows per logits tile
#define NTILE  12                 // tiles per batch (Tb <= 381)
#define NKS    24                 // 32-wide k-steps
#define NET    48                 // 16-wide e-tiles
#define P1_UNITS (B_ * NTILE * 2) // 768  (b, tile, e-half)

typedef _Float16 half8_t __attribute__((ext_vector_type(8)));
typedef float    f32x4   __attribute__((ext_vector_type(4)));

struct Args {
    const float* X; const int* lens; const float* W;
    const float* db; const float* ab; const float* q;
    const float* lnw; const float* lnb;
    float* cf; float* sent;
    int* starts; int* Tb; float* Lc;
    _Float16* Wt;      // [48 etile][24 ks][64 lane][8]  = 1.125 MB, frag-contiguous
    float* partial;    // [2 eh][32 b][512 t]
};

__device__ __forceinline__ float fast_tanh(float x) {
    float e = __expf(2.0f * x);
    return 1.0f - 2.0f / (e + 1.0f);   // exact saturation at +/-inf
}

// ---------------- k_prep: Wt transpose | per-batch scan | Lc ----------------
// bid 0..287   : Wt[et][ks][lane][j] = (fp16) W[et*16+(lane&15)][ks*32+(lane>>4)*8+j]
// bid 288..319 : exclusive scan of chunk_lens for batch bid-288
// bid 320      : Lc = sum_e q[e]*tanh(db[e]+ab[e])
__global__ __launch_bounds__(256) void k_prep(Args a) {
    const int tid = threadIdx.x, bid = blockIdx.x;
    if (bid < 288) {
        int u    = bid * 256 + tid;        // 0..73727 frag-words
        int lane = u & 63;
        int ks   = (u >> 6) % NKS;
        int et   = u / (64 * NKS);
        int e    = et * 16 + (lane & 15);
        int k    = ks * 32 + ((lane >> 4) << 3);
        const float* src = a.W + (size_t)e * D_ + k;
        float4 f0 = *(const float4*)src;
        float4 f1 = *(const float4*)(src + 4);
        half8_t h;
        h[0] = (_Float16)f0.x; h[1] = (_Float16)f0.y;
        h[2] = (_Float16)f0.z; h[3] = (_Float16)f0.w;
        h[4] = (_Float16)f1.x; h[5] = (_Float16)f1.y;
        h[6] = (_Float16)f1.z; h[7] = (_Float16)f1.w;
        *(half8_t*)(a.Wt + (size_t)u * 8) = h;    // coalesced write
    } else if (bid < 320) {
        int b = bid - 288;
        __shared__ int s_scan[256];
        int v = (tid < C_) ? a.lens[b * C_ + tid] : 0;
        s_scan[tid] = v;
        __syncthreads();
        #pragma unroll
        for (int off = 1; off < C_; off <<= 1) {
            int add = (tid >= off) ? s_scan[tid - off] : 0;
            __syncthreads();
            s_scan[tid] += add;
            __syncthreads();
        }
        if (tid < C_) {
            a.starts[b * C_ + tid] = s_scan[tid] - v;
            if (tid == C_ - 1) a.Tb[b] = s_scan[C_ - 1];
        }
    } else {
        __shared__ float s_lcred[256];
        float p = 0.f;
        for (int e = tid; e < D_; e += 256) p += fast_tanh(a.db[e] + a.ab[e]) * a.q[e];
        s_lcred[tid] = p;
        __syncthreads();
        for (int off = 128; off > 0; off >>= 1) {
            if (tid < off) s_lcred[tid] += s_lcred[tid + off];
            __syncthreads();
        }
        if (tid == 0) *a.Lc = s_lcred[0];
    }
}

// ---------------- k_logits ----------------
// logit[b,t] = sum_e q[e]*tanh( sum_d X[b,t,d]*W[e,d] + db[e]+ab[e] )
// Unit = (b, 32-row tile, e-half). X tile staged once to 48 KB LDS (fp16,
// XOR-swizzled, coalesced HBM read). K-loop: 2 ds_read A-frags + 6 COALESCED
// 1-KB Wt loads (L2-resident) + 12 MFMA -> acc[2][6].
// A-frag (16x16x32 f16): lane holds A[m0+mt*16+(l&15)][ks*32+(l>>4)*8+j]
// B-frag: lane holds W[e][same k], e = (etile)*16+(l&15)
// C/D: col=lane&15 (e), row=(lane>>4)*4+r (m)   [validated rounds 3-7]
__global__ __launch_bounds__(256) void k_logits(Args a) {
    __shared__ _Float16 Xs[MT * D_];   // 48 KB
    __shared__ float s_red[4][32];
    const int tid = threadIdx.x, lane = tid & 63, wid = tid >> 6;
    const int erow = lane & 15;
    const int krow = (lane >> 4) * 8;

    int u    = blockIdx.x;
    int b    = u / (NTILE * 2);
    int rem  = u % (NTILE * 2);
    int tile = rem >> 1;
    int eh   = rem & 1;
    int m0   = tile * MT;
    if (m0 >= a.Tb[b]) return;   // block-uniform

    // ---- stage X tile (32 rows x 768 k) fp32 -> fp16 LDS, swizzled ----
    {
        const float* Xb = a.X + ((size_t)(b * S_ + m0)) * D_;
        #pragma unroll
        for (int it = 0; it < 12; ++it) {
            int idx = it * 256 + tid;        // 0..3071 half8 units
            int row = idx / 96;
            int kk8 = idx % 96;
            const float* src = Xb + (size_t)row * D_ + kk8 * 8;
            float4 f0 = *(const float4*)src;
            float4 f1 = *(const float4*)(src + 4);
            half8_t h;
            h[0] = (_Float16)f0.x; h[1] = (_Float16)f0.y;
            h[2] = (_Float16)f0.z; h[3] = (_Float16)f0.w;
            h[4] = (_Float16)f1.x; h[5] = (_Float16)f1.y;
            h[6] = (_Float16)f1.z; h[7] = (_Float16)f1.w;
            int byte = row * 1536 + kk8 * 16;
            byte ^= (row & 7) << 4;
            *(half8_t*)((char*)Xs + byte) = h;
        }
    }
    __syncthreads();

    // ---- K loop: coalesced Wt frag loads + MFMA ----
    const int et0 = eh * 24 + wid * 6;   // this wave: 6 e-tiles = 96 cols
    const _Float16* Wb = a.Wt + (((size_t)et0 * NKS) * 64 + lane) * 8;
    f32x4 acc[2][6];
    #pragma unroll
    for (int mt = 0; mt < 2; ++mt)
        #pragma unroll
        for (int nt = 0; nt < 6; ++nt) acc[mt][nt] = (f32x4)(0.f);

    #pragma unroll 4
    for (int ks = 0; ks < NKS; ++ks) {
        half8_t av[2];
        #pragma unroll
        for (int mt = 0; mt < 2; ++mt) {
            int row  = mt * 16 + erow;
            int byte = row * 1536 + (ks * 32 + krow) * 2;
            byte ^= (row & 7) << 4;
            av[mt] = *(const half8_t*)((const char*)Xs + byte);
        }
        #pragma unroll
        for (int nt = 0; nt < 6; ++nt) {
            half8_t bv = *(const half8_t*)(Wb + ((size_t)nt * NKS + ks) * 64 * 8);
            acc[0][nt] = __builtin_amdgcn_mfma_f32_16x16x32_f16(av[0], bv, acc[0][nt], 0, 0, 0);
            acc[1][nt] = __builtin_amdgcn_mfma_f32_16x16x32_f16(av[1], bv, acc[1][nt], 0, 0, 0);
        }
    }

    // ---- epilogue: tanh + q-dot ----
    float lsum[2][4] = {{0.f,0.f,0.f,0.f},{0.f,0.f,0.f,0.f}};
    #pragma unroll
    for (int nt = 0; nt < 6; ++nt) {
        int e = (et0 + nt) * 16 + erow;
        float beta = a.db[e] + a.ab[e];
        float qe = a.q[e];
        #pragma unroll
        for (int r = 0; r < 4; ++r) {
            lsum[0][r] += fast_tanh(acc[0][nt][r] + beta) * qe;
            lsum[1][r] += fast_tanh(acc[1][nt][r] + beta) * qe;
        }
    }
    #pragma unroll
    for (int off = 1; off < 16; off <<= 1)
        #pragma unroll
        for (int mt = 0; mt < 2; ++mt)
            #pragma unroll
            for (int r = 0; r < 4; ++r)
                lsum[mt][r] += __shfl_xor(lsum[mt][r], off, 64);

    __syncthreads();
    if (erow == 0) {
        #pragma unroll
        for (int mt = 0; mt < 2; ++mt)
            #pragma unroll
            for (int r = 0; r < 4; ++r)
                s_red[wid][mt * 16 + (lane >> 4) * 4 + r] = lsum[mt][r];
    }
    __syncthreads();
    if (tid < MT)
        a.partial[((size_t)eh * B_ + b) * S_ + m0 + tid] =
            s_red[0][tid] + s_red[1][tid] + s_red[2][tid] + s_red[3][tid];
}

// ---------------- k_chunk: per-wave softmax + weighted sum + LayerNorm ----------------
__global__ __launch_bounds__(256) void k_chunk(Args a) {
    const int tid = threadIdx.x, lane = tid & 63, wid = tid >> 6;
    const float LcV = *a.Lc;
    const int gw = blockIdx.x * 4 + wid;
    const int nw = gridDim.x * 4;
    for (int cu = gw; cu < B_ * C_; cu += nw) {
        int b = cu >> 7, c = cu & 127;
        int len = a.lens[b * C_ + c];
        len = max(0, min(len, LCK));
        int start = a.starts[b * C_ + c];
        float lg[LCK];
        #pragma unroll
        for (int l = 0; l < LCK; ++l) {
            bool valid = l < len;
            int t = valid ? (start + l) : start;   // start <= 381 < 512: in-bounds
            float v = a.partial[(size_t)b * S_ + t] + a.partial[((size_t)B_ + b) * S_ + t];
            lg[l] = valid ? v : LcV;
        }
        float m = lg[0];
        #pragma unroll
        for (int l = 1; l < LCK; ++l) m = fmaxf(m, lg[l]);
        float denom = 0.f;
        #pragma unroll
        for (int l = 0; l < LCK; ++l) { lg[l] = __expf(lg[l] - m); denom += lg[l]; }
        float inv = 1.0f / denom;

        const float* Xb = a.X + (size_t)b * S_ * D_;
        f32x4 o[3] = {(f32x4)(0.f), (f32x4)(0.f), (f32x4)(0.f)};
        for (int l = 0; l < len; ++l) {
            const float* row = Xb + (size_t)(start + l) * D_;
            float wgt = lg[l];
            #pragma unroll
            for (int p = 0; p < 3; ++p) {
                f32x4 xv = *(const f32x4*)(row + p * 256 + lane * 4);
                o[p] += xv * wgt;
            }
        }
        float sum = 0.f, sq = 0.f;
        #pragma unroll
        for (int p = 0; p < 3; ++p) {
            o[p] *= inv;
            #pragma unroll
            for (int j = 0; j < 4; ++j) { sum += o[p][j]; sq += o[p][j] * o[p][j]; }
        }
        #pragma unroll
        for (int off = 1; off < 64; off <<= 1) {
            sum += __shfl_xor(sum, off, 64);
            sq  += __shfl_xor(sq,  off, 64);
        }
        float u_   = sum * (1.0f / D_);
        float var  = fmaxf(sq * (1.0f / D_) - u_ * u_, 0.0f);
        float rstd = rsqrtf(var + 1e-12f);
        float* out = a.cf + ((size_t)b * C_ + c) * D_;
        #pragma unroll
        for (int p = 0; p < 3; ++p) {
            int d = p * 256 + lane * 4;
            f32x4 wv = *(const f32x4*)(a.lnw + d);
            f32x4 bv = *(const f32x4*)(a.lnb + d);
            f32x4 ov;
            #pragma unroll
            for (int j = 0; j < 4; ++j) ov[j] = wv[j] * ((o[p][j] - u_) * rstd) + bv[j];
            *(f32x4*)(out + d) = ov;
        }
    }
}

// ---------------- k_max: sentence max over chunks ----------------
__global__ __launch_bounds__(256) void k_max(Args a) {
    int b = blockIdx.x;
    int d = blockIdx.y * 256 + threadIdx.x;
    const float* p = a.cf + (size_t)b * C_ * D_ + d;
    float m = -INFINITY;
    #pragma unroll 8
    for (int c = 0; c < C_; ++c) m = fmaxf(m, p[(size_t)c * D_]);
    a.sent[(size_t)b * D_ + d] = m;
}

extern "C" void kernel_launch(void* const* d_in, const int* in_sizes, int n_in,
                              void* d_out, int out_size, void* d_ws, size_t ws_size,
                              hipStream_t stream) {
    Args a;
    a.X    = (const float*)d_in[0];   // (32,512,768)
    a.lens = (const int*)d_in[1];     // (32,128)
    a.W    = (const float*)d_in[2];   // (768,768)
    a.db   = (const float*)d_in[3];
    a.ab   = (const float*)d_in[4];
    a.q    = (const float*)d_in[5];
    a.lnw  = (const float*)d_in[6];
    a.lnb  = (const float*)d_in[7];

    a.cf   = (float*)d_out;                      // (32,128,768)
    a.sent = a.cf + (size_t)B_ * C_ * D_;        // (32,768)

    a.starts  = (int*)d_ws;                                  // 16 KB
    a.Tb      = (int*)((char*)d_ws + 16384);                 // 128 B
    a.Lc      = (float*)((char*)d_ws + 16640);               // 4 B
    a.Wt      = (_Float16*)((char*)d_ws + 32768);            // 1.125 MB
    a.partial = (float*)((char*)d_ws + 32768 + 1179648);     // 128 KB

    k_prep  <<<321,       256, 0, stream>>>(a);
    k_logits<<<P1_UNITS,  256, 0, stream>>>(a);
    k_chunk <<<512,       256, 0, stream>>>(a);
    k_max   <<<dim3(B_, 3), 256, 0, stream>>>(a);
}